// Round 1
// baseline (14406.921 us; speedup 1.0000x reference)
//
#include <hip/hip_runtime.h>
#include <hip/hip_bf16.h>

#define Bc 4
#define Cc 128
#define Nn 4096
#define Kk 9

// ---------------------------------------------------------------------------
// K1: sq[b*N + n] = sum_c x[b][c][n]^2, sequential ascending FMA chain.
// MUST match k_gram_topk's accumulation order bitwise so self-distance == 0.
// ---------------------------------------------------------------------------
__global__ void k_sq(const float* __restrict__ x, float* __restrict__ sq) {
    int id = blockIdx.x * 256 + threadIdx.x;          // 16384 total
    int b = id >> 12, n = id & (Nn - 1);
    const float* xb = x + (size_t)b * Cc * Nn + n;
    float a = 0.f;
    #pragma unroll 8
    for (int c = 0; c < Cc; ++c) {
        float v = xb[(size_t)c * Nn];
        a = fmaf(v, v, a);
    }
    sq[id] = a;
}

// ---------------------------------------------------------------------------
// sorted-ascending top-9 insert, fully unrolled (static register indexing)
// ---------------------------------------------------------------------------
__device__ __forceinline__ void insert9(float (&d)[9], int (&ix)[9], float nd, int ni) {
    float cx = nd; int cI = ni;
    #pragma unroll
    for (int p = 0; p < 9; ++p) {
        bool lt = cx < d[p];
        float td = d[p]; int ti = ix[p];
        if (lt) { d[p] = cx; ix[p] = cI; cx = td; cI = ti; }
    }
}

// ---------------------------------------------------------------------------
// K2: Gram + top-9.  Block: 32 rows x all 4096 cols (64-col tiles), 256 thr.
// tx = t&7 -> cols tx+8j (j=0..7);  ty = t>>3 -> row ty.
// LDS 48KB: As 32x128, Bs 64x128, XOR-swizzled (chunk = row*32 + (c4 ^ (row&7)))
// so ds_read_b128 in the compute loop sits at the bank-cycle floor.
// idxOut layout: [b][k][n]  (n contiguous -> coalesced reads in k_gather)
// ---------------------------------------------------------------------------
__global__ __launch_bounds__(256, 2) void k_gram_topk(
        const float* __restrict__ x, const float* __restrict__ sq,
        int* __restrict__ idxOut) {
    const int t  = threadIdx.x;
    const int tx = t & 7;        // col group
    const int ty = t >> 3;       // 0..31 = row within tile
    const int bid = blockIdx.x;  // 512 blocks
    const int b = bid >> 7;
    const int rowbase = (bid & 127) * 32;
    const float* xb  = x + (size_t)b * Cc * Nn;
    const float* sqb = sq + b * Nn;

    __shared__ alignas(16) float As[32 * 128];
    __shared__ alignas(16) float Bs[64 * 128];

    // A tile: 32 rows x 128 c (swizzled). Loaded once per block.
    for (int k = t; k < 32 * 128; k += 256) {
        int i = k & 31;          // row
        int c = k >> 5;          // 0..127
        As[i * 128 + ((((c >> 2) ^ (i & 7)) << 2) | (c & 3))] =
            xb[(size_t)c * Nn + rowbase + i];
    }

    const float sqr = sqb[rowbase + ty];
    float cd[9]; int ci[9];
    #pragma unroll
    for (int p = 0; p < 9; ++p) { cd[p] = 3.4e38f; ci[p] = 0; }

    const float4* A4 = reinterpret_cast<const float4*>(As);
    const float4* B4 = reinterpret_cast<const float4*>(Bs);
    const int arow = ty * 32;
    const int ax = ty & 7;

    for (int tile = 0; tile < 64; ++tile) {
        const int colbase = tile * 64;
        __syncthreads();   // previous compute done before overwriting Bs
        for (int k = t; k < 64 * 128; k += 256) {
            int i = k & 63; int c = k >> 6;
            Bs[i * 128 + ((((c >> 2) ^ (i & 7)) << 2) | (c & 3))] =
                xb[(size_t)c * Nn + colbase + i];
        }
        __syncthreads();

        float acc[8];
        #pragma unroll
        for (int j = 0; j < 8; ++j) acc[j] = 0.f;

        for (int c4 = 0; c4 < 32; ++c4) {
            float4 a = A4[arow + (c4 ^ ax)];
            float af[4] = {a.x, a.y, a.z, a.w};
            const int bx = c4 ^ tx;          // (tx+8j)&7 == tx
            float4 bv[8];
            #pragma unroll
            for (int j = 0; j < 8; ++j) bv[j] = B4[(tx + 8 * j) * 32 + bx];
            #pragma unroll
            for (int e = 0; e < 4; ++e) {
                float ae = af[e];
                #pragma unroll
                for (int j = 0; j < 8; ++j) {
                    float be = (e == 0) ? bv[j].x : (e == 1) ? bv[j].y
                             : (e == 2) ? bv[j].z : bv[j].w;
                    acc[j] = fmaf(ae, be, acc[j]);   // c ascending: bitwise == k_sq
                }
            }
        }
        #pragma unroll
        for (int j = 0; j < 8; ++j) {
            int gcol = colbase + tx + 8 * j;
            float d2 = fmaf(-2.0f, acc[j], sqr + sqb[gcol]);
            if (d2 < cd[8]) insert9(cd, ci, d2, gcol);
        }
    }

    // merge the 8 per-thread lists of this row via shuffle butterfly
    // (the 8 lists live in 8 consecutive lanes: t = ty*8 + tx)
    #pragma unroll
    for (int m = 1; m < 8; m <<= 1) {
        float od[9]; int oi[9];
        #pragma unroll
        for (int p = 0; p < 9; ++p) {
            od[p] = __shfl_xor(cd[p], m);
            oi[p] = __shfl_xor(ci[p], m);
        }
        #pragma unroll
        for (int p = 0; p < 9; ++p)
            if (od[p] < cd[8]) insert9(cd, ci, od[p], oi[p]);
    }
    if (tx == 0) {
        int n = rowbase + ty;
        #pragma unroll
        for (int k = 0; k < 9; ++k)
            idxOut[((size_t)b * 9 + k) * Nn + n] = ci[k];
    }
}

// ---------------------------------------------------------------------------
// K3: h0[b][c][n] = (1+eps)*x[b][c][n] + sum_k x[b][c][idx[b][k][n]]
// one thread per output element; idx loads coalesced, gathers spatially local.
// ---------------------------------------------------------------------------
__global__ void k_gather(const float* __restrict__ x, const int* __restrict__ idx,
                         const float* __restrict__ epsp, float* __restrict__ h0) {
    int id = blockIdx.x * 256 + threadIdx.x;          // B*C*N = 2097152
    int n  = id & (Nn - 1);
    int bc = id >> 12;                                // b*C + c
    int b  = bc >> 7;
    const float* xr = x + (size_t)bc * Nn;
    const int* ib = idx + (size_t)b * 9 * Nn + n;
    float s = (1.0f + epsp[0]) * xr[n];
    #pragma unroll
    for (int k = 0; k < 9; ++k) s += xr[ib[(size_t)k * Nn]];
    h0[id] = s;
}

// ---------------------------------------------------------------------------
// K4/K5: out[b][d][n] = act( bias[d] + sum_c W[c][d] * in[b][c][n] )
// Block: 64 d x 64 n, 256 thr, 16 acc each; LDS 64KB swizzled.
// ---------------------------------------------------------------------------
template <bool RELU>
__global__ __launch_bounds__(256, 2) void k_mlp(
        const float* __restrict__ in, const float* __restrict__ W,
        const float* __restrict__ bias, float* __restrict__ out) {
    const int t  = threadIdx.x;
    const int td = t & 15;        // d chunk
    const int tn = t >> 4;        // n chunk (0..15)
    const int bid = blockIdx.x;   // B*2*64 = 512
    const int b = bid >> 7;
    const int dbase = ((bid >> 6) & 1) * 64;
    const int nb = (bid & 63) * 64;

    __shared__ alignas(16) float Ws[128 * 64];
    __shared__ alignas(16) float Hs[128 * 64];

    for (int k = t; k < 128 * 64; k += 256) {
        int i = k & 63; int c = k >> 6;
        int sw = c * 64 + ((((i >> 2) ^ (c & 7)) << 2) | (i & 3));
        Ws[sw] = W[c * 128 + dbase + i];
        Hs[sw] = in[((size_t)b * 128 + c) * Nn + nb + i];
    }
    __syncthreads();

    float acc[4][4];
    #pragma unroll
    for (int dd = 0; dd < 4; ++dd)
        #pragma unroll
        for (int nn = 0; nn < 4; ++nn) acc[dd][nn] = 0.f;

    const float4* W4 = reinterpret_cast<const float4*>(Ws);
    const float4* H4 = reinterpret_cast<const float4*>(Hs);
    for (int c = 0; c < 128; ++c) {
        int cx = c & 7;
        float4 w = W4[c * 16 + (td ^ cx)];
        float4 h = H4[c * 16 + (tn ^ cx)];
        float wf[4] = {w.x, w.y, w.z, w.w};
        float hf[4] = {h.x, h.y, h.z, h.w};
        #pragma unroll
        for (int dd = 0; dd < 4; ++dd)
            #pragma unroll
            for (int nn = 0; nn < 4; ++nn)
                acc[dd][nn] = fmaf(wf[dd], hf[nn], acc[dd][nn]);
    }

    #pragma unroll
    for (int dd = 0; dd < 4; ++dd) {
        int d = dbase + 4 * td + dd;
        float bb = bias[d];
        float4 o;
        o.x = acc[dd][0] + bb; o.y = acc[dd][1] + bb;
        o.z = acc[dd][2] + bb; o.w = acc[dd][3] + bb;
        if (RELU) {
            o.x = fmaxf(o.x, 0.f); o.y = fmaxf(o.y, 0.f);
            o.z = fmaxf(o.z, 0.f); o.w = fmaxf(o.w, 0.f);
        }
        *reinterpret_cast<float4*>(&out[((size_t)b * 128 + d) * Nn + nb + 4 * tn]) = o;
    }
}

// ---------------------------------------------------------------------------
// K6: per-channel batch-norm stats (biased var), 1 block per channel.
// scsh[e] = gamma*rsqrt(var+eps);  scsh[128+e] = beta - mean*scale
// ---------------------------------------------------------------------------
__global__ void k_bnstats(const float* __restrict__ o, const float* __restrict__ gamma,
                          const float* __restrict__ beta, float* __restrict__ scsh) {
    int e = blockIdx.x, t = threadIdx.x;
    float s = 0.f, s2 = 0.f;
    for (int b = 0; b < Bc; ++b) {
        const float* p = o + ((size_t)b * 128 + e) * Nn;
        for (int n = t; n < Nn; n += 256) {
            float v = p[n];
            s += v;
            s2 = fmaf(v, v, s2);
        }
    }
    __shared__ float rs[256], rq[256];
    rs[t] = s; rq[t] = s2;
    __syncthreads();
    for (int off = 128; off > 0; off >>= 1) {
        if (t < off) { rs[t] += rs[t + off]; rq[t] += rq[t + off]; }
        __syncthreads();
    }
    if (t == 0) {
        float mean = rs[0] * (1.0f / 16384.0f);
        float var  = rq[0] * (1.0f / 16384.0f) - mean * mean;
        if (var < 0.f) var = 0.f;
        float sc = gamma[e] * rsqrtf(var + 1e-5f);
        scsh[e] = sc;
        scsh[128 + e] = beta[e] - mean * sc;
    }
}

// ---------------------------------------------------------------------------
// K7: out = relu(scale[e]*o + shift[e] + x), in place on d_out, float4.
// ---------------------------------------------------------------------------
__global__ void k_bnapply(float* __restrict__ o, const float* __restrict__ x,
                          const float* __restrict__ scsh) {
    int id4 = blockIdx.x * 256 + threadIdx.x;         // 524288
    int e = (id4 >> 10) & 127;
    float sc = scsh[e], sh = scsh[128 + e];
    float4 v = reinterpret_cast<const float4*>(o)[id4];
    float4 r = reinterpret_cast<const float4*>(x)[id4];
    float4 w;
    w.x = fmaxf(fmaf(sc, v.x, sh) + r.x, 0.f);
    w.y = fmaxf(fmaf(sc, v.y, sh) + r.y, 0.f);
    w.z = fmaxf(fmaf(sc, v.z, sh) + r.z, 0.f);
    w.w = fmaxf(fmaf(sc, v.w, sh) + r.w, 0.f);
    reinterpret_cast<float4*>(o)[id4] = w;
}

// ---------------------------------------------------------------------------
extern "C" void kernel_launch(void* const* d_in, const int* in_sizes, int n_in,
                              void* d_out, int out_size, void* d_ws, size_t ws_size,
                              hipStream_t stream) {
    const float* x     = (const float*)d_in[0];
    const float* epsp  = (const float*)d_in[1];
    const float* W1    = (const float*)d_in[2];
    const float* b1    = (const float*)d_in[3];
    const float* W2    = (const float*)d_in[4];
    const float* b2    = (const float*)d_in[5];
    const float* gamma = (const float*)d_in[6];
    const float* beta  = (const float*)d_in[7];
    float* out = (float*)d_out;

    // workspace layout (floats): sq[16384] | idx[147456 ints] | h0[2097152] |
    // h1[2097152] | scsh[256]   -> ~17.4 MB total
    float* ws   = (float*)d_ws;
    float* sq   = ws;
    int*   idx  = (int*)(ws + 16384);
    float* h0   = ws + 16384 + (size_t)Bc * 9 * Nn;
    float* h1   = h0 + (size_t)Bc * Cc * Nn;
    float* scsh = h1 + (size_t)Bc * Cc * Nn;

    k_sq       <<<64,   256, 0, stream>>>(x, sq);
    k_gram_topk<<<512,  256, 0, stream>>>(x, sq, idx);
    k_gather   <<<8192, 256, 0, stream>>>(x, idx, epsp, h0);
    k_mlp<true> <<<512, 256, 0, stream>>>(h0, W1, b1, h1);
    k_mlp<false><<<512, 256, 0, stream>>>(h1, W2, b2, out);
    k_bnstats  <<<128,  256, 0, stream>>>(out, gamma, beta, scsh);
    k_bnapply  <<<2048, 256, 0, stream>>>(out, x, scsh);
}

// Round 5
// 919.226 us; speedup vs baseline: 15.6729x; 15.6729x over previous
//
#include <hip/hip_runtime.h>
#include <hip/hip_bf16.h>

#define Bc 4
#define Cc 128
#define Nn 4096
#define Kk 9

// ---------------------------------------------------------------------------
// K1: sq[b*N + n] = sum_c x[b][c][n]^2, sequential ascending FMA chain.
// MUST match k_gram_topk's accumulation order bitwise so self-distance == 0.
// ---------------------------------------------------------------------------
__global__ void k_sq(const float* __restrict__ x, float* __restrict__ sq) {
    int id = blockIdx.x * 256 + threadIdx.x;          // 16384 total
    int b = id >> 12, n = id & (Nn - 1);
    const float* xb = x + (size_t)b * Cc * Nn + n;
    float a = 0.f;
    #pragma unroll 8
    for (int c = 0; c < Cc; ++c) {
        float v = xb[(size_t)c * Nn];
        a = fmaf(v, v, a);
    }
    sq[id] = a;
}

// ---------------------------------------------------------------------------
// sorted-ascending top-9 insert, fully unrolled (static register indexing)
// ---------------------------------------------------------------------------
__device__ __forceinline__ void insert9(float (&d)[9], int (&ix)[9], float nd, int ni) {
    float cx = nd; int cI = ni;
    #pragma unroll
    for (int p = 0; p < 9; ++p) {
        bool lt = cx < d[p];
        float td = d[p]; int ti = ix[p];
        if (lt) { d[p] = cx; ix[p] = cI; cx = td; cI = ti; }
    }
}

// ---------------------------------------------------------------------------
// K2: Gram + top-9.  Block: 32 rows x all 4096 cols (64-col tiles), 256 thr.
// tx = t&7 -> cols tx+8j (j=0..7);  ty = t>>3 -> row ty.
// LDS: As 32x128, Bs 64x128 XOR-swizzled; sqs[64] stages the col norms.
// NOTE: no min-waves clause in launch_bounds — round-1 showed the 128-VGPR
// cap caused in-loop scratch spills (27 GB WRITE_SIZE, VALUBusy 4.7%).
// B fragments are loaded one float4 at a time to keep peak pressure low.
// idxOut layout: [b][k][n]  (n contiguous -> coalesced reads in k_gather)
// ---------------------------------------------------------------------------
__global__ __launch_bounds__(256) void k_gram_topk(
        const float* __restrict__ x, const float* __restrict__ sq,
        int* __restrict__ idxOut) {
    const int t  = threadIdx.x;
    const int tx = t & 7;        // col group
    const int ty = t >> 3;       // 0..31 = row within tile
    const int bid = blockIdx.x;  // 512 blocks
    const int b = bid >> 7;
    const int rowbase = (bid & 127) * 32;
    const float* xb  = x + (size_t)b * Cc * Nn;
    const float* sqb = sq + b * Nn;

    __shared__ alignas(16) float As[32 * 128];
    __shared__ alignas(16) float Bs[64 * 128];
    __shared__ float sqs[64];

    // A tile: 32 rows x 128 c (swizzled). Loaded once per block.
    for (int k = t; k < 32 * 128; k += 256) {
        int i = k & 31;          // row
        int c = k >> 5;          // 0..127
        As[i * 128 + ((((c >> 2) ^ (i & 7)) << 2) | (c & 3))] =
            xb[(size_t)c * Nn + rowbase + i];
    }

    const float sqr = sqb[rowbase + ty];
    float cd[9]; int ci[9];
    #pragma unroll
    for (int p = 0; p < 9; ++p) { cd[p] = 3.4e38f; ci[p] = 0; }

    const float4* A4 = reinterpret_cast<const float4*>(As);
    const float4* B4 = reinterpret_cast<const float4*>(Bs);
    const int arow = ty * 32;
    const int ax = ty & 7;

    for (int tile = 0; tile < 64; ++tile) {
        const int colbase = tile * 64;
        __syncthreads();   // previous compute done before overwriting Bs/sqs
        for (int k = t; k < 64 * 128; k += 256) {
            int i = k & 63; int c = k >> 6;
            Bs[i * 128 + ((((c >> 2) ^ (i & 7)) << 2) | (c & 3))] =
                xb[(size_t)c * Nn + colbase + i];
        }
        if (t < 64) sqs[t] = sqb[colbase + t];
        __syncthreads();

        float acc[8];
        #pragma unroll
        for (int j = 0; j < 8; ++j) acc[j] = 0.f;

        for (int c4 = 0; c4 < 32; ++c4) {
            float4 a = A4[arow + (c4 ^ ax)];
            const int bx = c4 ^ tx;          // (tx+8j)&7 == tx
            #pragma unroll
            for (int j = 0; j < 8; ++j) {
                float4 bv = B4[(tx + 8 * j) * 32 + bx];
                // per-acc chain: c = 4*c4+e ascending -> bitwise == k_sq chain
                acc[j] = fmaf(a.x, bv.x, acc[j]);
                acc[j] = fmaf(a.y, bv.y, acc[j]);
                acc[j] = fmaf(a.z, bv.z, acc[j]);
                acc[j] = fmaf(a.w, bv.w, acc[j]);
            }
        }
        #pragma unroll
        for (int j = 0; j < 8; ++j) {
            int lcol = tx + 8 * j;
            float d2 = fmaf(-2.0f, acc[j], sqr + sqs[lcol]);
            if (d2 < cd[8]) insert9(cd, ci, d2, colbase + lcol);
        }
    }

    // merge the 8 per-thread lists of this row via shuffle butterfly
    // (the 8 lists live in 8 consecutive lanes: t = ty*8 + tx)
    #pragma unroll
    for (int m = 1; m < 8; m <<= 1) {
        float od[9]; int oi[9];
        #pragma unroll
        for (int p = 0; p < 9; ++p) {
            od[p] = __shfl_xor(cd[p], m);
            oi[p] = __shfl_xor(ci[p], m);
        }
        #pragma unroll
        for (int p = 0; p < 9; ++p)
            if (od[p] < cd[8]) insert9(cd, ci, od[p], oi[p]);
    }
    if (tx == 0) {
        int n = rowbase + ty;
        #pragma unroll
        for (int k = 0; k < 9; ++k)
            idxOut[((size_t)b * 9 + k) * Nn + n] = ci[k];
    }
}

// ---------------------------------------------------------------------------
// K3: h0[b][c][n] = (1+eps)*x[b][c][n] + sum_k x[b][c][idx[b][k][n]]
// one thread per output element; idx loads coalesced, gathers spatially local.
// ---------------------------------------------------------------------------
__global__ void k_gather(const float* __restrict__ x, const int* __restrict__ idx,
                         const float* __restrict__ epsp, float* __restrict__ h0) {
    int id = blockIdx.x * 256 + threadIdx.x;          // B*C*N = 2097152
    int n  = id & (Nn - 1);
    int bc = id >> 12;                                // b*C + c
    int b  = bc >> 7;
    const float* xr = x + (size_t)bc * Nn;
    const int* ib = idx + (size_t)b * 9 * Nn + n;
    float s = (1.0f + epsp[0]) * xr[n];
    #pragma unroll
    for (int k = 0; k < 9; ++k) s += xr[ib[(size_t)k * Nn]];
    h0[id] = s;
}

// ---------------------------------------------------------------------------
// K4/K5: out[b][d][n] = act( bias[d] + sum_c W[c][d] * in[b][c][n] )
// Block: 64 d x 64 n, 256 thr, 16 acc each; LDS 64KB swizzled.
// ---------------------------------------------------------------------------
template <bool RELU>
__global__ __launch_bounds__(256, 2) void k_mlp(
        const float* __restrict__ in, const float* __restrict__ W,
        const float* __restrict__ bias, float* __restrict__ out) {
    const int t  = threadIdx.x;
    const int td = t & 15;        // d chunk
    const int tn = t >> 4;        // n chunk (0..15)
    const int bid = blockIdx.x;   // B*2*64 = 512
    const int b = bid >> 7;
    const int dbase = ((bid >> 6) & 1) * 64;
    const int nb = (bid & 63) * 64;

    __shared__ alignas(16) float Ws[128 * 64];
    __shared__ alignas(16) float Hs[128 * 64];

    for (int k = t; k < 128 * 64; k += 256) {
        int i = k & 63; int c = k >> 6;
        int sw = c * 64 + ((((i >> 2) ^ (c & 7)) << 2) | (i & 3));
        Ws[sw] = W[c * 128 + dbase + i];
        Hs[sw] = in[((size_t)b * 128 + c) * Nn + nb + i];
    }
    __syncthreads();

    float acc[4][4];
    #pragma unroll
    for (int dd = 0; dd < 4; ++dd)
        #pragma unroll
        for (int nn = 0; nn < 4; ++nn) acc[dd][nn] = 0.f;

    const float4* W4 = reinterpret_cast<const float4*>(Ws);
    const float4* H4 = reinterpret_cast<const float4*>(Hs);
    for (int c = 0; c < 128; ++c) {
        int cx = c & 7;
        float4 w = W4[c * 16 + (td ^ cx)];
        float4 h = H4[c * 16 + (tn ^ cx)];
        float wf[4] = {w.x, w.y, w.z, w.w};
        float hf[4] = {h.x, h.y, h.z, h.w};
        #pragma unroll
        for (int dd = 0; dd < 4; ++dd)
            #pragma unroll
            for (int nn = 0; nn < 4; ++nn)
                acc[dd][nn] = fmaf(wf[dd], hf[nn], acc[dd][nn]);
    }

    #pragma unroll
    for (int dd = 0; dd < 4; ++dd) {
        int d = dbase + 4 * td + dd;
        float bb = bias[d];
        float4 o;
        o.x = acc[dd][0] + bb; o.y = acc[dd][1] + bb;
        o.z = acc[dd][2] + bb; o.w = acc[dd][3] + bb;
        if (RELU) {
            o.x = fmaxf(o.x, 0.f); o.y = fmaxf(o.y, 0.f);
            o.z = fmaxf(o.z, 0.f); o.w = fmaxf(o.w, 0.f);
        }
        *reinterpret_cast<float4*>(&out[((size_t)b * 128 + d) * Nn + nb + 4 * tn]) = o;
    }
}

// ---------------------------------------------------------------------------
// K6: per-channel batch-norm stats (biased var), 1 block per channel.
// scsh[e] = gamma*rsqrt(var+eps);  scsh[128+e] = beta - mean*scale
// ---------------------------------------------------------------------------
__global__ void k_bnstats(const float* __restrict__ o, const float* __restrict__ gamma,
                          const float* __restrict__ beta, float* __restrict__ scsh) {
    int e = blockIdx.x, t = threadIdx.x;
    float s = 0.f, s2 = 0.f;
    for (int b = 0; b < Bc; ++b) {
        const float* p = o + ((size_t)b * 128 + e) * Nn;
        for (int n = t; n < Nn; n += 256) {
            float v = p[n];
            s += v;
            s2 = fmaf(v, v, s2);
        }
    }
    __shared__ float rs[256], rq[256];
    rs[t] = s; rq[t] = s2;
    __syncthreads();
    for (int off = 128; off > 0; off >>= 1) {
        if (t < off) { rs[t] += rs[t + off]; rq[t] += rq[t + off]; }
        __syncthreads();
    }
    if (t == 0) {
        float mean = rs[0] * (1.0f / 16384.0f);
        float var  = rq[0] * (1.0f / 16384.0f) - mean * mean;
        if (var < 0.f) var = 0.f;
        float sc = gamma[e] * rsqrtf(var + 1e-5f);
        scsh[e] = sc;
        scsh[128 + e] = beta[e] - mean * sc;
    }
}

// ---------------------------------------------------------------------------
// K7: out = relu(scale[e]*o + shift[e] + x), in place on d_out, float4.
// ---------------------------------------------------------------------------
__global__ void k_bnapply(float* __restrict__ o, const float* __restrict__ x,
                          const float* __restrict__ scsh) {
    int id4 = blockIdx.x * 256 + threadIdx.x;         // 524288
    int e = (id4 >> 10) & 127;
    float sc = scsh[e], sh = scsh[128 + e];
    float4 v = reinterpret_cast<const float4*>(o)[id4];
    float4 r = reinterpret_cast<const float4*>(x)[id4];
    float4 w;
    w.x = fmaxf(fmaf(sc, v.x, sh) + r.x, 0.f);
    w.y = fmaxf(fmaf(sc, v.y, sh) + r.y, 0.f);
    w.z = fmaxf(fmaf(sc, v.z, sh) + r.z, 0.f);
    w.w = fmaxf(fmaf(sc, v.w, sh) + r.w, 0.f);
    reinterpret_cast<float4*>(o)[id4] = w;
}

// ---------------------------------------------------------------------------
extern "C" void kernel_launch(void* const* d_in, const int* in_sizes, int n_in,
                              void* d_out, int out_size, void* d_ws, size_t ws_size,
                              hipStream_t stream) {
    const float* x     = (const float*)d_in[0];
    const float* epsp  = (const float*)d_in[1];
    const float* W1    = (const float*)d_in[2];
    const float* b1    = (const float*)d_in[3];
    const float* W2    = (const float*)d_in[4];
    const float* b2    = (const float*)d_in[5];
    const float* gamma = (const float*)d_in[6];
    const float* beta  = (const float*)d_in[7];
    float* out = (float*)d_out;

    // workspace layout (floats): sq[16384] | idx[147456 ints] | h0[2097152] |
    // h1[2097152] | scsh[256]   -> ~17.4 MB total
    float* ws   = (float*)d_ws;
    float* sq   = ws;
    int*   idx  = (int*)(ws + 16384);
    float* h0   = ws + 16384 + (size_t)Bc * 9 * Nn;
    float* h1   = h0 + (size_t)Bc * Cc * Nn;
    float* scsh = h1 + (size_t)Bc * Cc * Nn;

    k_sq       <<<64,   256, 0, stream>>>(x, sq);
    k_gram_topk<<<512,  256, 0, stream>>>(x, sq, idx);
    k_gather   <<<8192, 256, 0, stream>>>(x, idx, epsp, h0);
    k_mlp<true> <<<512, 256, 0, stream>>>(h0, W1, b1, h1);
    k_mlp<false><<<512, 256, 0, stream>>>(h1, W2, b2, out);
    k_bnstats  <<<128,  256, 0, stream>>>(out, gamma, beta, scsh);
    k_bnapply  <<<2048, 256, 0, stream>>>(out, x, scsh);
}

// Round 8
// 771.899 us; speedup vs baseline: 18.6643x; 1.1909x over previous
//
#include <hip/hip_runtime.h>
#include <hip/hip_bf16.h>

#define Bc 4
#define Cc 128
#define Nn 4096

// ---------------------------------------------------------------------------
// K1: sq[b*N + n] = sum_c x[b][c][n]^2, sequential ascending FMA chain.
// MUST match k_gram_topk's per-acc chain bitwise so self-distance == 0.
// ---------------------------------------------------------------------------
__global__ void k_sq(const float* __restrict__ x, float* __restrict__ sq) {
    int id = blockIdx.x * 256 + threadIdx.x;          // 16384 total
    int b = id >> 12, n = id & (Nn - 1);
    const float* xb = x + (size_t)b * Cc * Nn + n;
    float a = 0.f;
    #pragma unroll 8
    for (int c = 0; c < Cc; ++c) {
        float v = xb[(size_t)c * Nn];
        a = fmaf(v, v, a);
    }
    sq[id] = a;
}

// ---------------------------------------------------------------------------
// sorted-ascending top-9 insert, fully unrolled (static register indexing).
// Strict < : on ties the EARLIER-inserted stays first.
// ---------------------------------------------------------------------------
__device__ __forceinline__ void insert9(float (&d)[9], int (&ix)[9], float nd, int ni) {
    float cx = nd; int cI = ni;
    #pragma unroll
    for (int p = 0; p < 9; ++p) {
        bool lt = cx < d[p];
        float td = d[p]; int ti = ix[p];
        if (lt) { d[p] = cx; ix[p] = cI; cx = td; cI = ti; }
    }
}

// 5-bit chunk rotate: (hi3,lo2) -> (lo2,hi3). Bijective on 0..31. Compute
// reads land 2-way bank-conflicted (free per m136); staging writes 4-way.
__device__ __forceinline__ int rot5(int q) { return ((q >> 2) | ((q & 3) << 3)) & 31; }

// ---------------------------------------------------------------------------
// K2 v5: Gram + per-row top-9, 8x8 register blocking, 64KB static LDS.
// ROUND-6/7 BUG (identical absmax 4.65625 both rounds => deterministic, not
// launch config): each thread's lists cover only its tx column-slice, but all
// 16 threads sharing ty wrote the same pd/pi row -> same-wave store race,
// one slice won. FIX: cross-tx shuffle-butterfly merge (m=1,2,4,8; the 16
// co-owner lanes t=ty*16+tx are consecutive within one wave), tx==0 writes.
// Grid: 256 blocks = 4 batches x 32 row-groups x 2 column-halves.
// Block: 128 rows x 2048 cols (16 tiles of 128 cols); tx=t&15 owns 8 cols,
// ty=t>>4 owns 8 rows -> 64 acc. LDS: A[64c][128r] + B[64c][128c] 32KB each,
// channel-split per tile (stage c-half, compute, repeat). Natural [c][n]
// layout -> staging is pure coalesced float4 copy; chunks rot5-swizzled.
// Per-acc chain: one fmaf per channel, c ascending == k_sq chain bitwise.
// ---------------------------------------------------------------------------
__global__ __launch_bounds__(256, 1) void k_gram_topk(
        const float* __restrict__ x, const float* __restrict__ sq,
        float* __restrict__ pd, int* __restrict__ pi) {
    __shared__ alignas(16) float As[64 * 128];   // 32KB
    __shared__ alignas(16) float Bs[64 * 128];   // 32KB
    float4* A4 = (float4*)As;
    float4* B4 = (float4*)Bs;

    const int t  = threadIdx.x;
    const int tx = t & 15;
    const int ty = t >> 4;
    const int bid = blockIdx.x;               // b*64 + rg*2 + half
    const int b    = bid >> 6;
    const int rg   = (bid >> 1) & 31;
    const int half = bid & 1;
    const int rowbase = rg * 128;
    const int colhalf = half * 2048;
    const float* xb  = x + (size_t)b * Cc * Nn;
    const float* sqb = sq + b * Nn;

    float rown[8];
    #pragma unroll
    for (int i = 0; i < 8; ++i) rown[i] = sqb[rowbase + ty * 8 + i];

    float cd[8][9]; int ci[8][9];
    #pragma unroll
    for (int i = 0; i < 8; ++i)
        #pragma unroll
        for (int p = 0; p < 9; ++p) { cd[i][p] = 3.4e38f; ci[i][p] = 0; }

    const int ra0 = rot5(ty * 2), ra1 = rot5(ty * 2 + 1);
    const int rb0 = rot5(tx * 2), rb1 = rot5(tx * 2 + 1);

    for (int tile = 0; tile < 16; ++tile) {
        const int colbase = colhalf + tile * 128;

        float acc[8][8];
        #pragma unroll
        for (int i = 0; i < 8; ++i)
            #pragma unroll
            for (int j = 0; j < 8; ++j) acc[i][j] = 0.f;

        #pragma unroll
        for (int ch = 0; ch < 2; ++ch) {
            __syncthreads();                  // prior compute done
            #pragma unroll
            for (int j = 0; j < 8; ++j) {
                int idx = t + j * 256;        // 0..2047
                int cl = idx >> 5, q = idx & 31;
                const float* src = xb + (size_t)(ch * 64 + cl) * Nn;
                A4[cl * 32 + rot5(q)] = *(const float4*)&src[rowbase + q * 4];
                B4[cl * 32 + rot5(q)] = *(const float4*)&src[colbase + q * 4];
            }
            __syncthreads();

            #pragma unroll 4
            for (int cl = 0; cl < 64; ++cl) {
                float4 a0 = A4[cl * 32 + ra0];    // rows ty*8+0..3
                float4 a1 = A4[cl * 32 + ra1];    // rows ty*8+4..7
                float4 b0 = B4[cl * 32 + rb0];    // cols tx*8+0..3
                float4 b1 = B4[cl * 32 + rb1];    // cols tx*8+4..7
                float av[8] = {a0.x, a0.y, a0.z, a0.w, a1.x, a1.y, a1.z, a1.w};
                float bv[8] = {b0.x, b0.y, b0.z, b0.w, b1.x, b1.y, b1.z, b1.w};
                #pragma unroll
                for (int i = 0; i < 8; ++i)
                    #pragma unroll
                    for (int j = 0; j < 8; ++j)
                        acc[i][j] = fmaf(av[i], bv[j], acc[i][j]); // c-ascending
            }
        }

        float4 cn0 = *(const float4*)&sqb[colbase + tx * 8];
        float4 cn1 = *(const float4*)&sqb[colbase + tx * 8 + 4];
        float cn[8] = {cn0.x, cn0.y, cn0.z, cn0.w, cn1.x, cn1.y, cn1.z, cn1.w};
        #pragma unroll
        for (int i = 0; i < 8; ++i)
            #pragma unroll
            for (int j = 0; j < 8; ++j) {
                float d2 = fmaf(-2.0f, acc[i][j], rown[i] + cn[j]);
                if (d2 < cd[i][8]) insert9(cd[i], ci[i], d2, colbase + tx * 8 + j);
            }
    }

    // cross-tx merge: the 16 lanes sharing ty each hold a disjoint column
    // slice of the same 8 rows. Butterfly over tx bits (all within one wave).
    #pragma unroll
    for (int m = 1; m < 16; m <<= 1) {
        #pragma unroll
        for (int i = 0; i < 8; ++i) {
            float od[9]; int oi[9];
            #pragma unroll
            for (int p = 0; p < 9; ++p) {
                od[p] = __shfl_xor(cd[i][p], m);
                oi[p] = __shfl_xor(ci[i][p], m);
            }
            #pragma unroll
            for (int p = 0; p < 9; ++p)
                if (od[p] < cd[i][8]) insert9(cd[i], ci[i], od[p], oi[p]);
        }
    }

    // partial lists: pd/pi[b][half][k][n], single writer per row (tx==0)
    if (tx == 0) {
        #pragma unroll
        for (int i = 0; i < 8; ++i) {
            int n = rowbase + ty * 8 + i;
            #pragma unroll
            for (int k = 0; k < 9; ++k) {
                size_t o = (((size_t)b * 2 + half) * 9 + k) * Nn + n;
                pd[o] = cd[i][k];
                pi[o] = ci[i][k];
            }
        }
    }
}

// ---------------------------------------------------------------------------
// K2b: merge the two column-half top-9 lists per row. Half-0 cols < half-1
// cols, so strict-< insertion keeps lower indices first on ties (stable).
// ---------------------------------------------------------------------------
__global__ void k_merge(const float* __restrict__ pd, const int* __restrict__ pi,
                        int* __restrict__ idxOut) {
    int id = blockIdx.x * 256 + threadIdx.x;  // 16384
    int b = id >> 12, n = id & (Nn - 1);
    float d0[9]; int i0[9];
    #pragma unroll
    for (int k = 0; k < 9; ++k) {
        size_t o = (((size_t)b * 2 + 0) * 9 + k) * Nn + n;
        d0[k] = pd[o]; i0[k] = pi[o];
    }
    #pragma unroll
    for (int k = 0; k < 9; ++k) {
        size_t o = (((size_t)b * 2 + 1) * 9 + k) * Nn + n;
        float dv = pd[o]; int iv = pi[o];
        if (dv < d0[8]) insert9(d0, i0, dv, iv);
    }
    #pragma unroll
    for (int k = 0; k < 9; ++k)
        idxOut[((size_t)b * 9 + k) * Nn + n] = i0[k];
}

// ---------------------------------------------------------------------------
// K3: h0[b][c][n] = (1+eps)*x[b][c][n] + sum_k x[b][c][idx[b][k][n]]
// ---------------------------------------------------------------------------
__global__ void k_gather(const float* __restrict__ x, const int* __restrict__ idx,
                         const float* __restrict__ epsp, float* __restrict__ h0) {
    int id = blockIdx.x * 256 + threadIdx.x;          // B*C*N = 2097152
    int n  = id & (Nn - 1);
    int bc = id >> 12;                                // b*C + c
    int b  = bc >> 7;
    const float* xr = x + (size_t)bc * Nn;
    const int* ib = idx + (size_t)b * 9 * Nn + n;
    float s = (1.0f + epsp[0]) * xr[n];
    #pragma unroll
    for (int k = 0; k < 9; ++k) s += xr[ib[(size_t)k * Nn]];
    h0[id] = s;
}

// ---------------------------------------------------------------------------
// K4/K5: out[b][d][n] = act( bias[d] + sum_c W[c][d] * in[b][c][n] )
// ---------------------------------------------------------------------------
template <bool RELU>
__global__ __launch_bounds__(256, 2) void k_mlp(
        const float* __restrict__ in, const float* __restrict__ W,
        const float* __restrict__ bias, float* __restrict__ out) {
    const int t  = threadIdx.x;
    const int td = t & 15;
    const int tn = t >> 4;
    const int bid = blockIdx.x;   // B*2*64 = 512
    const int b = bid >> 7;
    const int dbase = ((bid >> 6) & 1) * 64;
    const int nb = (bid & 63) * 64;

    __shared__ alignas(16) float Ws[128 * 64];
    __shared__ alignas(16) float Hs[128 * 64];

    for (int k = t; k < 128 * 64; k += 256) {
        int i = k & 63; int c = k >> 6;
        int sw = c * 64 + ((((i >> 2) ^ (c & 7)) << 2) | (i & 3));
        Ws[sw] = W[c * 128 + dbase + i];
        Hs[sw] = in[((size_t)b * 128 + c) * Nn + nb + i];
    }
    __syncthreads();

    float acc[4][4];
    #pragma unroll
    for (int dd = 0; dd < 4; ++dd)
        #pragma unroll
        for (int nn = 0; nn < 4; ++nn) acc[dd][nn] = 0.f;

    const float4* W4 = reinterpret_cast<const float4*>(Ws);
    const float4* H4 = reinterpret_cast<const float4*>(Hs);
    for (int c = 0; c < 128; ++c) {
        int cx = c & 7;
        float4 w = W4[c * 16 + (td ^ cx)];
        float4 h = H4[c * 16 + (tn ^ cx)];
        float wf[4] = {w.x, w.y, w.z, w.w};
        float hf[4] = {h.x, h.y, h.z, h.w};
        #pragma unroll
        for (int dd = 0; dd < 4; ++dd)
            #pragma unroll
            for (int nn = 0; nn < 4; ++nn)
                acc[dd][nn] = fmaf(wf[dd], hf[nn], acc[dd][nn]);
    }

    #pragma unroll
    for (int dd = 0; dd < 4; ++dd) {
        int d = dbase + 4 * td + dd;
        float bb = bias[d];
        float4 o;
        o.x = acc[dd][0] + bb; o.y = acc[dd][1] + bb;
        o.z = acc[dd][2] + bb; o.w = acc[dd][3] + bb;
        if (RELU) {
            o.x = fmaxf(o.x, 0.f); o.y = fmaxf(o.y, 0.f);
            o.z = fmaxf(o.z, 0.f); o.w = fmaxf(o.w, 0.f);
        }
        *reinterpret_cast<float4*>(&out[((size_t)b * 128 + d) * Nn + nb + 4 * tn]) = o;
    }
}

// ---------------------------------------------------------------------------
// K6: per-channel batch-norm stats (biased var), 1 block per channel.
// ---------------------------------------------------------------------------
__global__ void k_bnstats(const float* __restrict__ o, const float* __restrict__ gamma,
                          const float* __restrict__ beta, float* __restrict__ scsh) {
    int e = blockIdx.x, t = threadIdx.x;
    float s = 0.f, s2 = 0.f;
    for (int b = 0; b < Bc; ++b) {
        const float* p = o + ((size_t)b * 128 + e) * Nn;
        for (int n = t; n < Nn; n += 256) {
            float v = p[n];
            s += v;
            s2 = fmaf(v, v, s2);
        }
    }
    __shared__ float rs[256], rq[256];
    rs[t] = s; rq[t] = s2;
    __syncthreads();
    for (int off = 128; off > 0; off >>= 1) {
        if (t < off) { rs[t] += rs[t + off]; rq[t] += rq[t + off]; }
        __syncthreads();
    }
    if (t == 0) {
        float mean = rs[0] * (1.0f / 16384.0f);
        float var  = rq[0] * (1.0f / 16384.0f) - mean * mean;
        if (var < 0.f) var = 0.f;
        float sc = gamma[e] * rsqrtf(var + 1e-5f);
        scsh[e] = sc;
        scsh[128 + e] = beta[e] - mean * sc;
    }
}

// ---------------------------------------------------------------------------
// K7: out = relu(scale[e]*o + shift[e] + x), in place on d_out, float4.
// ---------------------------------------------------------------------------
__global__ void k_bnapply(float* __restrict__ o, const float* __restrict__ x,
                          const float* __restrict__ scsh) {
    int id4 = blockIdx.x * 256 + threadIdx.x;         // 524288
    int e = (id4 >> 10) & 127;
    float sc = scsh[e], sh = scsh[128 + e];
    float4 v = reinterpret_cast<const float4*>(o)[id4];
    float4 r = reinterpret_cast<const float4*>(x)[id4];
    float4 w;
    w.x = fmaxf(fmaf(sc, v.x, sh) + r.x, 0.f);
    w.y = fmaxf(fmaf(sc, v.y, sh) + r.y, 0.f);
    w.z = fmaxf(fmaf(sc, v.z, sh) + r.z, 0.f);
    w.w = fmaxf(fmaf(sc, v.w, sh) + r.w, 0.f);
    reinterpret_cast<float4*>(o)[id4] = w;
}

// ---------------------------------------------------------------------------
extern "C" void kernel_launch(void* const* d_in, const int* in_sizes, int n_in,
                              void* d_out, int out_size, void* d_ws, size_t ws_size,
                              hipStream_t stream) {
    const float* x     = (const float*)d_in[0];
    const float* epsp  = (const float*)d_in[1];
    const float* W1    = (const float*)d_in[2];
    const float* b1    = (const float*)d_in[3];
    const float* W2    = (const float*)d_in[4];
    const float* b2    = (const float*)d_in[5];
    const float* gamma = (const float*)d_in[6];
    const float* beta  = (const float*)d_in[7];
    float* out = (float*)d_out;

    // workspace (floats): sq[16384] | idx[147456] | h0[2097152] | h1[2097152]
    // | scsh[256]  (~17.4 MB). pd/pi (294912 each) alias h1: consumed by
    // k_merge before k_mlp<true> first writes h1.
    float* ws   = (float*)d_ws;
    float* sq   = ws;
    int*   idx  = (int*)(ws + 16384);
    float* h0   = ws + 16384 + (size_t)Bc * 9 * Nn;
    float* h1   = h0 + (size_t)Bc * Cc * Nn;
    float* scsh = h1 + (size_t)Bc * Cc * Nn;
    float* pd   = h1;                          // [4][2][9][4096]
    int*   pi   = (int*)(h1 + (size_t)Bc * 2 * 9 * Nn);

    k_sq        <<<64,   256, 0, stream>>>(x, sq);
    k_gram_topk <<<256,  256, 0, stream>>>(x, sq, pd, pi);
    k_merge     <<<64,   256, 0, stream>>>(pd, pi, idx);
    k_gather    <<<8192, 256, 0, stream>>>(x, idx, epsp, h0);
    k_mlp<true> <<<512,  256, 0, stream>>>(h0, W1, b1, h1);
    k_mlp<false><<<512,  256, 0, stream>>>(h1, W2, b2, out);
    k_bnstats   <<<128,  256, 0, stream>>>(out, gamma, beta, scsh);
    k_bnapply   <<<2048, 256, 0, stream>>>(out, x, scsh);
}